// Round 7
// baseline (768.445 us; speedup 1.0000x reference)
//
#include <hip/hip_runtime.h>

#define HDIM 128
#define BN_EPS 1e-5f
#define SCAN_BINS 1024
#define LSTR 136   // LDS row stride in shorts (mult of 8 -> 16B-aligned rows)
#define MROWS 16   // rows per tile (40000/16 = 2500 tiles, no tail)
#define NREP 8     // BN stat accumulator replicas (per-line atomic pressure /8)
#define PGRID 2048 // persistent grid: 8 blocks/CU x 256 CUs, co-residency forced
                   // by __launch_bounds__(256,8) (VGPR<=64, LDS 9.7KB*8<160KB)

typedef short short8 __attribute__((ext_vector_type(8)));
typedef float floatx4 __attribute__((ext_vector_type(4)));

__device__ __forceinline__ unsigned short f2b(float f) {
    union { float f; unsigned u; } v; v.f = f;
    unsigned r = v.u + 0x7FFFu + ((v.u >> 16) & 1u);   // RNE
    return (unsigned short)(r >> 16);
}

__device__ __forceinline__ float b2f(unsigned short b) {
    union { unsigned u; float f; } v; v.u = (unsigned)b << 16;
    return v.f;
}

// ---------------------------------------------------------------------------
// prep: convert x/W1/W2 -> bf16 + histogram targets (atomicAdd return IS the
// edge's rank -> stored free). Block 0 zeroes dummy row xB[N]; block 1 zeroes
// BN stat replicas.
// ---------------------------------------------------------------------------
__global__ __launch_bounds__(256) void prep_kernel(
    const float* __restrict__ x, unsigned short* __restrict__ xB, long n4,
    const float* __restrict__ W1, const float* __restrict__ W2,
    unsigned short* __restrict__ W1B, unsigned short* __restrict__ W2B,
    const int* __restrict__ eidx, int* __restrict__ hist,
    int* __restrict__ rank, float* __restrict__ statSum, int E, int N)
{
    int tid = blockIdx.x * 256 + threadIdx.x;
    int stride = gridDim.x * 256;
    if (blockIdx.x == 0 && threadIdx.x < 32) {
        ushort4 z; z.x = 0; z.y = 0; z.z = 0; z.w = 0;
        ((ushort4*)(xB + (size_t)N * HDIM))[threadIdx.x] = z;
    }
    if (blockIdx.x == 1) {
        for (int i = threadIdx.x; i < 2 * NREP * HDIM; i += 256)
            statSum[i] = 0.f;
    }
    for (long i = tid; i < n4; i += stride) {
        float4 v = ((const float4*)x)[i];
        ushort4 o;
        o.x = f2b(v.x); o.y = f2b(v.y); o.z = f2b(v.z); o.w = f2b(v.w);
        ((ushort4*)xB)[i] = o;
    }
    for (int i = tid; i < HDIM * HDIM; i += stride) {
        W1B[i] = f2b(W1[i]);
        W2B[i] = f2b(W2[i]);
    }
    int E4 = E >> 2;
    const int4* tgt4 = (const int4*)(eidx + E);
    for (int e4 = tid; e4 < E4; e4 += stride) {
        int4 t = tgt4[e4];
        int4 r;
        r.x = atomicAdd(&hist[t.x], 1);
        r.y = atomicAdd(&hist[t.y], 1);
        r.z = atomicAdd(&hist[t.z], 1);
        r.w = atomicAdd(&hist[t.w], 1);
        ((int4*)rank)[e4] = r;
    }
    for (int e = E4 * 4 + tid; e < E; e += stride) {
        rank[e] = atomicAdd(&hist[eidx[E + e]], 1);
    }
}

// ---------------------------------------------------------------------------
// Fused scan (level-1 + spin barrier + level-2 + pad fill) in ONE dispatch.
// NB=40 blocks: trivially co-resident -> internal spin barrier is safe.
// Padded bucket sizes (roundup8); pad slots filled with dummy row N.
// ---------------------------------------------------------------------------
__global__ __launch_bounds__(256) void scan_fused_kernel(
    const int* __restrict__ hist, int* __restrict__ offsets,
    int* __restrict__ blockSums, int* __restrict__ spin,
    int* __restrict__ srcSorted, int N, int NB)
{
    __shared__ int ts[256];
    __shared__ int bs[64];
    __shared__ int sPr;
    int b = blockIdx.x, t = threadIdx.x;
    int base = b * SCAN_BINS + t * 4;
    int4 h = make_int4(0, 0, 0, 0);
    if (base + 3 < N) {
        h = *(const int4*)(hist + base);
    } else {
        if (base + 0 < N) h.x = hist[base + 0];
        if (base + 1 < N) h.y = hist[base + 1];
        if (base + 2 < N) h.z = hist[base + 2];
    }
    int4 p;   // padded sizes
    p.x = (h.x + 7) & ~7;
    p.y = (h.y + 7) & ~7;
    p.z = (h.z + 7) & ~7;
    p.w = (h.w + 7) & ~7;
    int s = p.x + p.y + p.z + p.w;
    ts[t] = s;
    __syncthreads();
    for (int off = 1; off < 256; off <<= 1) {
        int v = ts[t];
        int add = (t >= off) ? ts[t - off] : 0;
        __syncthreads();
        ts[t] = v + add;
        __syncthreads();
    }
    int excl = ts[t] - s;
    // --- cross-block barrier: publish block total, wait for all ---
    if (t == 0) {
        blockSums[b] = ts[255];
        __threadfence();                 // release block total
        atomicAdd(spin, 1);
        while (__hip_atomic_load(spin, __ATOMIC_ACQUIRE,
                                 __HIP_MEMORY_SCOPE_AGENT) < NB) {
            __builtin_amdgcn_s_sleep(8);
        }
    }
    __syncthreads();
    if (t < NB) bs[t] = blockSums[t];
    __syncthreads();
    if (t == 0) {
        int pr = 0;
        for (int i = 0; i < b; i++) pr += bs[i];
        sPr = pr;
        if (b == 0) {
            int tot = 0;
            for (int i = 0; i < NB; i++) tot += bs[i];
            offsets[N] = tot;
        }
    }
    __syncthreads();
    int prefix = sPr;
    int4 o;
    o.x = prefix + excl;
    o.y = o.x + p.x;
    o.z = o.y + p.y;
    o.w = o.z + p.z;
    if (base + 3 < N) {
        *(int4*)(offsets + base) = o;
    } else {
        if (base + 0 < N) offsets[base + 0] = o.x;
        if (base + 1 < N) offsets[base + 1] = o.y;
        if (base + 2 < N) offsets[base + 2] = o.z;
    }
    for (int q = o.x + h.x; q < o.x + p.x; q++) srcSorted[q] = N;
    for (int q = o.y + h.y; q < o.y + p.y; q++) srcSorted[q] = N;
    for (int q = o.z + h.z; q < o.z + p.z; q++) srcSorted[q] = N;
    for (int q = o.w + h.w; q < o.w + p.w; q++) srcSorted[q] = N;
}

// Single-pass atomic-free reorder: position = offsets[tgt] + rank[e]
__global__ __launch_bounds__(256) void reorder_kernel(
    const int* __restrict__ eidx, const int* __restrict__ offsets,
    const int* __restrict__ rank, int* __restrict__ srcSorted, int E)
{
    int stride = gridDim.x * 256;
    for (int e = blockIdx.x * 256 + threadIdx.x; e < E; e += stride) {
        int t = eidx[E + e];
        srcSorted[offsets[t] + rank[e]] = eidx[e];
    }
}

// ---------------------------------------------------------------------------
// megabn (round-17): PERSISTENT plain kernel (no cooperative launch).
// grid = min(2048, ntiles); __launch_bounds__(256,8) forces <=64 VGPR so
// 8 blocks/CU x 256 CUs = 2048 co-resident is guaranteed -> in-kernel spin
// barrier is safe. Phase 1 grid-strides 16-row tiles (verified R5 pipeline);
// fence+barrier; phase 2 BN-rescales the same tiles (L2-hot, no re-read
// dispatch).
// ---------------------------------------------------------------------------
__global__ __launch_bounds__(256, 8) void megabn_kernel(
    const unsigned short* __restrict__ xB,
    const int* __restrict__ offsets, const int* __restrict__ srcSorted,
    const float* __restrict__ eps,
    const unsigned short* __restrict__ W1B, const float* __restrict__ b1,
    const unsigned short* __restrict__ W2B, const float* __restrict__ b2,
    const float* __restrict__ gamma, const float* __restrict__ beta,
    float* __restrict__ out, float* __restrict__ statSum,
    float* __restrict__ statSqs, int* __restrict__ spin,
    int N, int ntiles, int nblk)
{
    __shared__ unsigned short sA[MROWS * LSTR];   // agg tile (bf16)
    __shared__ unsigned short sH[MROWS * LSTR];   // h1 tile (bf16)
    __shared__ float sSc[HDIM];
    __shared__ float sSh[HDIM];

    int tid = threadIdx.x;
    float coef = 1.0f + eps[0];
    int tx = tid & 15, ty = tid >> 4;   // 16 col-lanes x 16 rows
    int col = tx * 8;
    int w = tid >> 6;
    int l = tid & 63;
    int m = l & 15, quad = l >> 4;
    int cbase = w * 32;
    float* repSum = statSum + (blockIdx.x & (NREP - 1)) * HDIM;
    float* repSqs = statSqs + (blockIdx.x & (NREP - 1)) * HDIM;

    // ---- phase 1: aggregate + GEMM1 + GEMM2 + BN stats, per tile ----
    for (int tile = blockIdx.x; tile < ntiles; tile += nblk) {
        int rb = tile * MROWS;

        // A: aggregate 16 rows into sA
        {
            int row = rb + ty;
            float acc[8] = {0.f, 0.f, 0.f, 0.f, 0.f, 0.f, 0.f, 0.f};
            if (row < N) {
                short8 xv = *(const short8*)(xB + (size_t)row * HDIM + col);
                #pragma unroll
                for (int j = 0; j < 8; j++) acc[j] = coef * b2f((unsigned short)xv[j]);
                int beg = offsets[row];
                int nb = (offsets[row + 1] - beg) >> 3;   // padded: exact batches
                const int4* sp = (const int4*)(srcSorted + beg);  // beg % 8 == 0
                int4 ia, ib;
                if (nb > 0) { ia = sp[0]; ib = sp[1]; }
                for (int b = 0; b < nb; b++) {
                    short8 u[8];
                    u[0] = *(const short8*)(xB + (size_t)ia.x * HDIM + col);
                    u[1] = *(const short8*)(xB + (size_t)ia.y * HDIM + col);
                    u[2] = *(const short8*)(xB + (size_t)ia.z * HDIM + col);
                    u[3] = *(const short8*)(xB + (size_t)ia.w * HDIM + col);
                    u[4] = *(const short8*)(xB + (size_t)ib.x * HDIM + col);
                    u[5] = *(const short8*)(xB + (size_t)ib.y * HDIM + col);
                    u[6] = *(const short8*)(xB + (size_t)ib.z * HDIM + col);
                    u[7] = *(const short8*)(xB + (size_t)ib.w * HDIM + col);
                    sp += 2;
                    if (b + 1 < nb) { ia = sp[0]; ib = sp[1]; }  // prefetch next
                    #pragma unroll
                    for (int q = 0; q < 8; q++)
                        #pragma unroll
                        for (int j = 0; j < 8; j++)
                            acc[j] += b2f((unsigned short)u[q][j]);
                }
            }
            short8 o;
            #pragma unroll
            for (int j = 0; j < 8; j++) o[j] = (short)f2b(acc[j]);
            *(short8*)(sA + ty * LSTR + col) = o;
        }
        __syncthreads();

        // B: GEMM1 from sA; each wave owns 32 output cols
        floatx4 acc1[2];
        #pragma unroll
        for (int t = 0; t < 2; t++) acc1[t] = (floatx4){0.f, 0.f, 0.f, 0.f};
        #pragma unroll
        for (int kk = 0; kk < 4; kk++) {
            int k0 = kk * 32 + quad * 8;
            short8 a = *(const short8*)(sA + m * LSTR + k0);
            #pragma unroll
            for (int t = 0; t < 2; t++) {
                short8 bfr = *(const short8*)(W1B + (size_t)(cbase + t * 16 + m) * HDIM + k0);
                acc1[t] = __builtin_amdgcn_mfma_f32_16x16x32_bf16(a, bfr, acc1[t], 0, 0, 0);
            }
        }
        #pragma unroll
        for (int t = 0; t < 2; t++) {
            int colc = cbase + t * 16 + m;
            float bs = b1[colc];
            #pragma unroll
            for (int r = 0; r < 4; r++) {
                float v = fmaxf(acc1[t][r] + bs, 0.f);
                sH[(quad * 4 + r) * LSTR + colc] = f2b(v);
            }
        }
        __syncthreads();   // all col-slices of h1 ready before GEMM2 reads K=128

        // C: GEMM2 from sH + b2 -> out (pre-BN), BN stats (replicated)
        floatx4 acc2[2];
        #pragma unroll
        for (int t = 0; t < 2; t++) acc2[t] = (floatx4){0.f, 0.f, 0.f, 0.f};
        #pragma unroll
        for (int kk = 0; kk < 4; kk++) {
            int k0 = kk * 32 + quad * 8;
            short8 a = *(const short8*)(sH + m * LSTR + k0);
            #pragma unroll
            for (int t = 0; t < 2; t++) {
                short8 bfr = *(const short8*)(W2B + (size_t)(cbase + t * 16 + m) * HDIM + k0);
                acc2[t] = __builtin_amdgcn_mfma_f32_16x16x32_bf16(a, bfr, acc2[t], 0, 0, 0);
            }
        }
        int row0 = rb + quad * 4;
        #pragma unroll
        for (int t = 0; t < 2; t++) {
            int colc = cbase + t * 16 + m;
            float bs = b2[colc];
            float cs = 0.f, cq = 0.f;
            #pragma unroll
            for (int r = 0; r < 4; r++) {
                int row = row0 + r;
                if (row < N) {
                    float v = acc2[t][r] + bs;
                    out[(size_t)row * HDIM + colc] = v;
                    cs += v; cq += v * v;
                }
            }
            cs += __shfl_xor(cs, 16, 64);
            cs += __shfl_xor(cs, 32, 64);
            cq += __shfl_xor(cq, 16, 64);
            cq += __shfl_xor(cq, 32, 64);
            if (quad == 0) {
                atomicAdd(&repSum[colc], cs);
                atomicAdd(&repSqs[colc], cq);
            }
        }
        __syncthreads();   // sA/sH reuse safe for next tile
    }

    // ---- grid-wide spin barrier (all nblk blocks co-resident) ----
    if (tid == 0) {
        __threadfence();                 // release stats + out writes
        atomicAdd(spin, 1);
        while (__hip_atomic_load(spin, __ATOMIC_ACQUIRE,
                                 __HIP_MEMORY_SCOPE_AGENT) < nblk) {
            __builtin_amdgcn_s_sleep(8);
        }
    }
    __syncthreads();

    // ---- phase 2: BN scale/shift, rescale own (L2-hot) tiles ----
    if (tid < HDIM) {
        float s = 0.f, q = 0.f;
        #pragma unroll
        for (int r = 0; r < NREP; r++) {
            s += statSum[r * HDIM + tid];
            q += statSqs[r * HDIM + tid];
        }
        float invN = 1.0f / (float)N;
        float mean = s * invN;
        float var = q * invN - mean * mean;
        float sc = gamma[tid] * rsqrtf(var + BN_EPS);
        sSc[tid] = sc;
        sSh[tid] = beta[tid] - mean * sc;
    }
    __syncthreads();
    float4* o4 = (float4*)out;
    for (int tile = blockIdx.x; tile < ntiles; tile += nblk) {
        long base4 = (long)tile * (MROWS * HDIM / 4);   // 512 float4 per tile
        #pragma unroll
        for (int k = 0; k < 2; k++) {
            long i = base4 + k * 256 + tid;
            int ch = (int)(i & 31) * 4;
            float4 v = o4[i];
            v.x = fmaxf(v.x * sSc[ch + 0] + sSh[ch + 0], 0.f);
            v.y = fmaxf(v.y * sSc[ch + 1] + sSh[ch + 1], 0.f);
            v.z = fmaxf(v.z * sSc[ch + 2] + sSh[ch + 2], 0.f);
            v.w = fmaxf(v.w * sSc[ch + 3] + sSh[ch + 3], 0.f);
            o4[i] = v;
        }
    }
}

extern "C" void kernel_launch(void* const* d_in, const int* in_sizes, int n_in,
                              void* d_out, int out_size, void* d_ws, size_t ws_size,
                              hipStream_t stream) {
    const float* x     = (const float*)d_in[0];
    const int*   eidx  = (const int*)d_in[1];
    const float* eps   = (const float*)d_in[2];
    const float* W1    = (const float*)d_in[3];
    const float* b1    = (const float*)d_in[4];
    const float* W2    = (const float*)d_in[5];
    const float* b2    = (const float*)d_in[6];
    const float* gamma = (const float*)d_in[7];
    const float* beta  = (const float*)d_in[8];
    float* out = (float*)d_out;

    int N = in_sizes[0] / HDIM;
    int E = in_sizes[1] / 2;
    size_t NH = (size_t)N * HDIM;
    int NB = (N + SCAN_BINS - 1) / SCAN_BINS;
    int NpadOff = (N + 1 + 3) & ~3;
    long n4 = (long)NH / 4;
    int Emax = E + 7 * N + 64;   // padded srcSorted capacity

    unsigned short* xB   = (unsigned short*)d_ws;   // (N+1)*H  (+1 dummy row)
    unsigned short* W1B  = xB + NH + HDIM;          // H*H
    unsigned short* W2B  = W1B + HDIM * HDIM;       // H*H
    float* statSum = (float*)(W2B + HDIM * HDIM);   // NREP*H
    float* statSqs = statSum + NREP * HDIM;         // NREP*H
    int*   hist    = (int*)(statSqs + NREP * HDIM); // N
    int*   spin    = hist + N;                      // 16 (barrier counters)
    int*   offsets = spin + 16;                     // NpadOff
    int*   rank    = offsets + NpadOff;             // E
    int*   srcSorted = rank + E;                    // Emax
    int*   blockSums = srcSorted + Emax;            // 64

    int ntiles = (N + MROWS - 1) / MROWS;
    int nblk = ntiles < PGRID ? ntiles : PGRID;
    int* spinScan = spin;
    int* spinMega = spin + 4;

    // 1. zero hist + spin counters (contiguous)
    hipMemsetAsync(hist, 0, (size_t)(N + 16) * sizeof(int), stream);
    // 2. convert + histogram (rank from atomicAdd return) + stat zeroing
    prep_kernel<<<1280, 256, 0, stream>>>(x, xB, n4, W1, W2, W1B, W2B,
                                          eidx, hist, rank, statSum, E, N);
    // 3. fused scan: level-1 + internal spin barrier + level-2 + pad fill
    scan_fused_kernel<<<NB, 256, 0, stream>>>(hist, offsets, blockSums,
                                              spinScan, srcSorted, N, NB);
    // 4. single-pass atomic-free reorder
    reorder_kernel<<<1024, 256, 0, stream>>>(eidx, offsets, rank, srcSorted, E);
    // 5. persistent mega + spin barrier + BN apply (plain launch, graph-safe)
    megabn_kernel<<<nblk, 256, 0, stream>>>(
        xB, offsets, srcSorted, eps, W1B, b1, W2B, b2, gamma, beta,
        out, statSum, statSqs, spinMega, N, ntiles, nblk);
}

// Round 8
// 174.312 us; speedup vs baseline: 4.4084x; 4.4084x over previous
//
#include <hip/hip_runtime.h>

#define HDIM 128
#define BN_EPS 1e-5f
#define SCAN_BINS 1024
#define LSTR 136   // LDS row stride in shorts (mult of 8 -> 16B-aligned rows)
#define MROWS 16   // rows per mega block (40000/16 = 2500 blocks, no tail)
#define NREP 8     // BN stat accumulator replicas (per-line atomic pressure /8)

typedef short short8 __attribute__((ext_vector_type(8)));
typedef float floatx4 __attribute__((ext_vector_type(4)));

__device__ __forceinline__ unsigned short f2b(float f) {
    union { float f; unsigned u; } v; v.f = f;
    unsigned r = v.u + 0x7FFFu + ((v.u >> 16) & 1u);   // RNE
    return (unsigned short)(r >> 16);
}

__device__ __forceinline__ float b2f(unsigned short b) {
    union { unsigned u; float f; } v; v.u = (unsigned)b << 16;
    return v.f;
}

// ---------------------------------------------------------------------------
// prep: convert x/W1/W2 -> bf16 + histogram targets (atomicAdd return IS the
// edge's rank -> stored free). Block 0 zeroes dummy row xB[N]; block 1 zeroes
// BN stat replicas.
// ---------------------------------------------------------------------------
__global__ __launch_bounds__(256) void prep_kernel(
    const float* __restrict__ x, unsigned short* __restrict__ xB, long n4,
    const float* __restrict__ W1, const float* __restrict__ W2,
    unsigned short* __restrict__ W1B, unsigned short* __restrict__ W2B,
    const int* __restrict__ eidx, int* __restrict__ hist,
    int* __restrict__ rank, float* __restrict__ statSum, int E, int N)
{
    int tid = blockIdx.x * 256 + threadIdx.x;
    int stride = gridDim.x * 256;
    if (blockIdx.x == 0 && threadIdx.x < 32) {
        ushort4 z; z.x = 0; z.y = 0; z.z = 0; z.w = 0;
        ((ushort4*)(xB + (size_t)N * HDIM))[threadIdx.x] = z;
    }
    if (blockIdx.x == 1) {
        for (int i = threadIdx.x; i < 2 * NREP * HDIM; i += 256)
            statSum[i] = 0.f;
    }
    for (long i = tid; i < n4; i += stride) {
        float4 v = ((const float4*)x)[i];
        ushort4 o;
        o.x = f2b(v.x); o.y = f2b(v.y); o.z = f2b(v.z); o.w = f2b(v.w);
        ((ushort4*)xB)[i] = o;
    }
    for (int i = tid; i < HDIM * HDIM; i += stride) {
        W1B[i] = f2b(W1[i]);
        W2B[i] = f2b(W2[i]);
    }
    int E4 = E >> 2;
    const int4* tgt4 = (const int4*)(eidx + E);
    for (int e4 = tid; e4 < E4; e4 += stride) {
        int4 t = tgt4[e4];
        int4 r;
        r.x = atomicAdd(&hist[t.x], 1);
        r.y = atomicAdd(&hist[t.y], 1);
        r.z = atomicAdd(&hist[t.z], 1);
        r.w = atomicAdd(&hist[t.w], 1);
        ((int4*)rank)[e4] = r;
    }
    for (int e = E4 * 4 + tid; e < E; e += stride) {
        rank[e] = atomicAdd(&hist[eidx[E + e]], 1);
    }
}

// ---------------------------------------------------------------------------
// Fused scan (level-1 + spin barrier + level-2 + pad fill) in ONE dispatch.
// NB=40 blocks: trivially co-resident, tiny poll population -> spin is safe
// (verified R7). Padded sizes (roundup8); pad slots filled with dummy row N.
// ---------------------------------------------------------------------------
__global__ __launch_bounds__(256) void scan_fused_kernel(
    const int* __restrict__ hist, int* __restrict__ offsets,
    int* __restrict__ blockSums, int* __restrict__ spin,
    int* __restrict__ srcSorted, int N, int NB)
{
    __shared__ int ts[256];
    __shared__ int bs[64];
    __shared__ int sPr;
    int b = blockIdx.x, t = threadIdx.x;
    int base = b * SCAN_BINS + t * 4;
    int4 h = make_int4(0, 0, 0, 0);
    if (base + 3 < N) {
        h = *(const int4*)(hist + base);
    } else {
        if (base + 0 < N) h.x = hist[base + 0];
        if (base + 1 < N) h.y = hist[base + 1];
        if (base + 2 < N) h.z = hist[base + 2];
    }
    int4 p;   // padded sizes
    p.x = (h.x + 7) & ~7;
    p.y = (h.y + 7) & ~7;
    p.z = (h.z + 7) & ~7;
    p.w = (h.w + 7) & ~7;
    int s = p.x + p.y + p.z + p.w;
    ts[t] = s;
    __syncthreads();
    for (int off = 1; off < 256; off <<= 1) {
        int v = ts[t];
        int add = (t >= off) ? ts[t - off] : 0;
        __syncthreads();
        ts[t] = v + add;
        __syncthreads();
    }
    int excl = ts[t] - s;
    // --- cross-block barrier: publish block total, wait for all ---
    if (t == 0) {
        blockSums[b] = ts[255];
        __threadfence();                 // release block total
        atomicAdd(spin, 1);
        while (__hip_atomic_load(spin, __ATOMIC_ACQUIRE,
                                 __HIP_MEMORY_SCOPE_AGENT) < NB) {
            __builtin_amdgcn_s_sleep(8);
        }
    }
    __syncthreads();
    if (t < NB) bs[t] = blockSums[t];
    __syncthreads();
    if (t == 0) {
        int pr = 0;
        for (int i = 0; i < b; i++) pr += bs[i];
        sPr = pr;
        if (b == 0) {
            int tot = 0;
            for (int i = 0; i < NB; i++) tot += bs[i];
            offsets[N] = tot;
        }
    }
    __syncthreads();
    int prefix = sPr;
    int4 o;
    o.x = prefix + excl;
    o.y = o.x + p.x;
    o.z = o.y + p.y;
    o.w = o.z + p.z;
    if (base + 3 < N) {
        *(int4*)(offsets + base) = o;
    } else {
        if (base + 0 < N) offsets[base + 0] = o.x;
        if (base + 1 < N) offsets[base + 1] = o.y;
        if (base + 2 < N) offsets[base + 2] = o.z;
    }
    for (int q = o.x + h.x; q < o.x + p.x; q++) srcSorted[q] = N;
    for (int q = o.y + h.y; q < o.y + p.y; q++) srcSorted[q] = N;
    for (int q = o.z + h.z; q < o.z + p.z; q++) srcSorted[q] = N;
    for (int q = o.w + h.w; q < o.w + p.w; q++) srcSorted[q] = N;
}

// Single-pass atomic-free reorder: position = offsets[tgt] + rank[e]
__global__ __launch_bounds__(256) void reorder_kernel(
    const int* __restrict__ eidx, const int* __restrict__ offsets,
    const int* __restrict__ rank, int* __restrict__ srcSorted, int E)
{
    int stride = gridDim.x * 256;
    for (int e = blockIdx.x * 256 + threadIdx.x; e < E; e += stride) {
        int t = eidx[E + e];
        srcSorted[offsets[t] + rank[e]] = eidx[e];
    }
}

// ---------------------------------------------------------------------------
// mega_kernel (R5's verified-best variant: under the 43.5us top-5 cutoff):
// 16 rows/block = 2500 blocks, launch_bounds(256,8), branch-free batch-8
// gather with one-batch index prefetch, bf16 self-term.
//   A: aggregate 16 rows -> LDS tile sA
//   B: GEMM1 (each wave: shared 16 rows x its own 32 cols); relu+b1 -> sH
//   C: GEMM2 + b2 -> out (fp32, pre-BN) + BN stats to replicated global slots
// ---------------------------------------------------------------------------
__global__ __launch_bounds__(256, 8) void mega_kernel(
    const unsigned short* __restrict__ xB,
    const int* __restrict__ offsets, const int* __restrict__ srcSorted,
    const float* __restrict__ eps,
    const unsigned short* __restrict__ W1B, const float* __restrict__ b1,
    const unsigned short* __restrict__ W2B, const float* __restrict__ b2,
    float* __restrict__ out, float* __restrict__ statSum,
    float* __restrict__ statSqs, int N)
{
    __shared__ unsigned short sA[MROWS * LSTR];   // agg tile (bf16)
    __shared__ unsigned short sH[MROWS * LSTR];   // h1 tile (bf16)

    int tid = threadIdx.x;
    int rb = blockIdx.x * MROWS;

    // ---- A: aggregate 16 rows into sA ----
    float coef = 1.0f + eps[0];
    int tx = tid & 15, ty = tid >> 4;   // 16 col-lanes x 16 rows
    int col = tx * 8;
    {
        int row = rb + ty;
        float acc[8] = {0.f, 0.f, 0.f, 0.f, 0.f, 0.f, 0.f, 0.f};
        if (row < N) {
            short8 xv = *(const short8*)(xB + (size_t)row * HDIM + col);
            #pragma unroll
            for (int j = 0; j < 8; j++) acc[j] = coef * b2f((unsigned short)xv[j]);
            int beg = offsets[row];
            int nb = (offsets[row + 1] - beg) >> 3;   // padded: exact batches
            const int4* sp = (const int4*)(srcSorted + beg);  // beg % 8 == 0
            int4 ia, ib;
            if (nb > 0) { ia = sp[0]; ib = sp[1]; }
            for (int b = 0; b < nb; b++) {
                short8 u[8];
                u[0] = *(const short8*)(xB + (size_t)ia.x * HDIM + col);
                u[1] = *(const short8*)(xB + (size_t)ia.y * HDIM + col);
                u[2] = *(const short8*)(xB + (size_t)ia.z * HDIM + col);
                u[3] = *(const short8*)(xB + (size_t)ia.w * HDIM + col);
                u[4] = *(const short8*)(xB + (size_t)ib.x * HDIM + col);
                u[5] = *(const short8*)(xB + (size_t)ib.y * HDIM + col);
                u[6] = *(const short8*)(xB + (size_t)ib.z * HDIM + col);
                u[7] = *(const short8*)(xB + (size_t)ib.w * HDIM + col);
                sp += 2;
                if (b + 1 < nb) { ia = sp[0]; ib = sp[1]; }  // prefetch next
                #pragma unroll
                for (int q = 0; q < 8; q++)
                    #pragma unroll
                    for (int j = 0; j < 8; j++)
                        acc[j] += b2f((unsigned short)u[q][j]);
            }
        }
        short8 o;
        #pragma unroll
        for (int j = 0; j < 8; j++) o[j] = (short)f2b(acc[j]);
        *(short8*)(sA + ty * LSTR + col) = o;
    }
    __syncthreads();

    // ---- B: GEMM1 from sA; each wave owns 32 output cols of the 16 rows ----
    int w = tid >> 6;
    int l = tid & 63;
    int m = l & 15, quad = l >> 4;
    int cbase = w * 32;

    floatx4 acc1[2];
    #pragma unroll
    for (int t = 0; t < 2; t++) acc1[t] = (floatx4){0.f, 0.f, 0.f, 0.f};
    #pragma unroll
    for (int kk = 0; kk < 4; kk++) {
        int k0 = kk * 32 + quad * 8;
        short8 a = *(const short8*)(sA + m * LSTR + k0);
        #pragma unroll
        for (int t = 0; t < 2; t++) {
            short8 bfr = *(const short8*)(W1B + (size_t)(cbase + t * 16 + m) * HDIM + k0);
            acc1[t] = __builtin_amdgcn_mfma_f32_16x16x32_bf16(a, bfr, acc1[t], 0, 0, 0);
        }
    }
    #pragma unroll
    for (int t = 0; t < 2; t++) {
        int colc = cbase + t * 16 + m;
        float bs = b1[colc];
        #pragma unroll
        for (int r = 0; r < 4; r++) {
            float v = fmaxf(acc1[t][r] + bs, 0.f);
            sH[(quad * 4 + r) * LSTR + colc] = f2b(v);
        }
    }
    __syncthreads();   // all col-slices of h1 ready before GEMM2 reads K=128

    // ---- C: GEMM2 from sH + b2 -> out (pre-BN), BN stats (replicated) ----
    floatx4 acc2[2];
    #pragma unroll
    for (int t = 0; t < 2; t++) acc2[t] = (floatx4){0.f, 0.f, 0.f, 0.f};
    #pragma unroll
    for (int kk = 0; kk < 4; kk++) {
        int k0 = kk * 32 + quad * 8;
        short8 a = *(const short8*)(sH + m * LSTR + k0);
        #pragma unroll
        for (int t = 0; t < 2; t++) {
            short8 bfr = *(const short8*)(W2B + (size_t)(cbase + t * 16 + m) * HDIM + k0);
            acc2[t] = __builtin_amdgcn_mfma_f32_16x16x32_bf16(a, bfr, acc2[t], 0, 0, 0);
        }
    }
    float* repSum = statSum + (blockIdx.x & (NREP - 1)) * HDIM;
    float* repSqs = statSqs + (blockIdx.x & (NREP - 1)) * HDIM;
    int row0 = rb + quad * 4;
    #pragma unroll
    for (int t = 0; t < 2; t++) {
        int colc = cbase + t * 16 + m;
        float bs = b2[colc];
        float cs = 0.f, cq = 0.f;
        #pragma unroll
        for (int r = 0; r < 4; r++) {
            int row = row0 + r;
            if (row < N) {
                float v = acc2[t][r] + bs;
                out[(size_t)row * HDIM + colc] = v;
                cs += v; cq += v * v;
            }
        }
        cs += __shfl_xor(cs, 16, 64);
        cs += __shfl_xor(cs, 32, 64);
        cq += __shfl_xor(cq, 16, 64);
        cq += __shfl_xor(cq, 32, 64);
        if (quad == 0) {
            atomicAdd(&repSum[colc], cs);
            atomicAdd(&repSqs[colc], cq);
        }
    }
}

// ---------------------------------------------------------------------------
// BN apply: fold NREP stat replicas, per-block scale/shift in LDS, then
// float4 in-place scale+shift+relu
// ---------------------------------------------------------------------------
__global__ __launch_bounds__(256) void bn_apply_kernel(
    float* __restrict__ out, const float* __restrict__ statSum,
    const float* __restrict__ statSqs, const float* __restrict__ gamma,
    const float* __restrict__ beta, int N, long n4)
{
    __shared__ float sSc[HDIM];
    __shared__ float sSh[HDIM];
    int t = threadIdx.x;
    if (t < HDIM) {
        float s = 0.f, q = 0.f;
        #pragma unroll
        for (int r = 0; r < NREP; r++) {
            s += statSum[r * HDIM + t];
            q += statSqs[r * HDIM + t];
        }
        float invN = 1.0f / (float)N;
        float mean = s * invN;
        float var = q * invN - mean * mean;
        float sc = gamma[t] * rsqrtf(var + BN_EPS);
        sSc[t] = sc;
        sSh[t] = beta[t] - mean * sc;
    }
    __syncthreads();
    long stride = (long)gridDim.x * 256;
    for (long i = (long)blockIdx.x * 256 + t; i < n4; i += stride) {
        int cg = (int)(i & 31) * 4;
        float4 v = ((float4*)out)[i];
        v.x = fmaxf(v.x * sSc[cg + 0] + sSh[cg + 0], 0.f);
        v.y = fmaxf(v.y * sSc[cg + 1] + sSh[cg + 1], 0.f);
        v.z = fmaxf(v.z * sSc[cg + 2] + sSh[cg + 2], 0.f);
        v.w = fmaxf(v.w * sSc[cg + 3] + sSh[cg + 3], 0.f);
        ((float4*)out)[i] = v;
    }
}

extern "C" void kernel_launch(void* const* d_in, const int* in_sizes, int n_in,
                              void* d_out, int out_size, void* d_ws, size_t ws_size,
                              hipStream_t stream) {
    const float* x     = (const float*)d_in[0];
    const int*   eidx  = (const int*)d_in[1];
    const float* eps   = (const float*)d_in[2];
    const float* W1    = (const float*)d_in[3];
    const float* b1    = (const float*)d_in[4];
    const float* W2    = (const float*)d_in[5];
    const float* b2    = (const float*)d_in[6];
    const float* gamma = (const float*)d_in[7];
    const float* beta  = (const float*)d_in[8];
    float* out = (float*)d_out;

    int N = in_sizes[0] / HDIM;
    int E = in_sizes[1] / 2;
    size_t NH = (size_t)N * HDIM;
    int NB = (N + SCAN_BINS - 1) / SCAN_BINS;
    int NpadOff = (N + 1 + 3) & ~3;
    long n4 = (long)NH / 4;
    int Emax = E + 7 * N + 64;   // padded srcSorted capacity

    unsigned short* xB   = (unsigned short*)d_ws;   // (N+1)*H  (+1 dummy row)
    unsigned short* W1B  = xB + NH + HDIM;          // H*H
    unsigned short* W2B  = W1B + HDIM * HDIM;       // H*H
    float* statSum = (float*)(W2B + HDIM * HDIM);   // NREP*H
    float* statSqs = statSum + NREP * HDIM;         // NREP*H
    int*   hist    = (int*)(statSqs + NREP * HDIM); // N
    int*   spin    = hist + N;                      // 16 (barrier counter)
    int*   offsets = spin + 16;                     // NpadOff
    int*   rank    = offsets + NpadOff;             // E
    int*   srcSorted = rank + E;                    // Emax
    int*   blockSums = srcSorted + Emax;            // 64

    // 1. zero hist + spin counter (contiguous)
    hipMemsetAsync(hist, 0, (size_t)(N + 16) * sizeof(int), stream);
    // 2. convert + histogram (rank from atomicAdd return) + stat zeroing
    prep_kernel<<<1280, 256, 0, stream>>>(x, xB, n4, W1, W2, W1B, W2B,
                                          eidx, hist, rank, statSum, E, N);
    // 3. fused scan: level-1 + 40-block spin barrier + level-2 + pad fill
    scan_fused_kernel<<<NB, 256, 0, stream>>>(hist, offsets, blockSums,
                                              spin, srcSorted, N, NB);
    // 4. single-pass atomic-free reorder
    reorder_kernel<<<1024, 256, 0, stream>>>(eidx, offsets, rank, srcSorted, E);
    // 5. aggregate + GEMM1 + GEMM2 + BN stats (16 rows/block, R5-verified)
    int gblocks = (N + MROWS - 1) / MROWS;
    mega_kernel<<<gblocks, 256, 0, stream>>>(
        xB, offsets, srcSorted, eps, W1B, b1, W2B, b2,
        out, statSum, statSqs, N);
    // 6. BN scale/shift + apply + final ReLU
    bn_apply_kernel<<<2048, 256, 0, stream>>>(
        out, statSum, statSqs, gamma, beta, N, n4);
}